// Round 1
// baseline (205.823 us; speedup 1.0000x reference)
//
#include <hip/hip_runtime.h>
#include <stdint.h>

#define NB 32
#define NN 2048
#define NR 100
#define NW 64   // 2048 bits / 32 = 64 u32 words per suppression row

__device__ __forceinline__ uint32_t ordered_f32(float f) {
    uint32_t u = __float_as_uint(f);
    return (u & 0x80000000u) ? ~u : (u | 0x80000000u);
}

// ---------------------------------------------------------------------------
// Kernel A: per-batch stable sort by descending score.
// Key = (~ordered(score) << 32) | index, ascending bitonic sort in LDS.
// Emits sorted (l,t,r,b) as float4 per box.
// ---------------------------------------------------------------------------
__global__ __launch_bounds__(1024) void nms_sort(const float* __restrict__ pred,
                                                 float4* __restrict__ sortedBox) {
    __shared__ uint64_t sk[NN];
    const int b   = blockIdx.x;
    const int tid = threadIdx.x;
    const float* p = pred + (size_t)b * NN * 5;

    for (int i = tid; i < NN; i += 1024) {
        float sc = p[i * 5 + 0];
        uint32_t k32 = ~ordered_f32(sc);           // ascending key == descending score
        sk[i] = ((uint64_t)k32 << 32) | (uint32_t)i;
    }
    __syncthreads();

    for (int k = 2; k <= NN; k <<= 1) {
        for (int j = k >> 1; j > 0; j >>= 1) {
            for (int i = tid; i < NN; i += 1024) {
                int ixj = i ^ j;
                if (ixj > i) {
                    uint64_t a = sk[i], c = sk[ixj];
                    bool up = ((i & k) == 0);
                    if ((a > c) == up) { sk[i] = c; sk[ixj] = a; }
                }
            }
            __syncthreads();
        }
    }

    for (int s = tid; s < NN; s += 1024) {
        int idx = (int)(uint32_t)sk[s];
        const float* q = p + idx * 5;
        sortedBox[(size_t)b * NN + s] = make_float4(q[1], q[2], q[3], q[4]);
    }
}

// ---------------------------------------------------------------------------
// Kernel B: suppression bit matrix. M[b][i] row of 64 u32 words, bit j set iff
// (j > i) && (inter(i,j)/area_j >= 0.5)  [exact fp semantics vs reference].
// One row-half per thread: box_j reads are wave-uniform LDS broadcasts.
// ---------------------------------------------------------------------------
__global__ __launch_bounds__(256) void nms_pairs(const float4* __restrict__ sortedBox,
                                                 uint32_t* __restrict__ M) {
    __shared__ float sL[NN], sT[NN], sR[NN], sD[NN], sA[NN];
    const int b    = blockIdx.y;
    const int tile = blockIdx.x;           // 16 tiles x 128 rows
    const int tid  = threadIdx.x;
    const float4* box = sortedBox + (size_t)b * NN;

    for (int s = tid; s < NN; s += 256) {
        float4 v = box[s];
        sL[s] = v.x; sT[s] = v.y; sR[s] = v.z; sD[s] = v.w;
        sA[s] = (v.z - v.x) * (v.w - v.y);
    }
    __syncthreads();

    const int i     = tile * 128 + (tid >> 1);
    const int jhalf = (tid & 1);           // 0: j in [0,1024)   1: j in [1024,2048)
    const float li = sL[i], ti = sT[i], ri = sR[i], bi = sD[i];
    uint32_t* Mrow = M + ((size_t)b * NN + i) * NW + jhalf * 32;

    for (int w = 0; w < 32; ++w) {
        const int j0 = jhalf * 1024 + w * 32;
        uint32_t word = 0;
        if (j0 + 31 > i) {                 // else whole word is j<=i -> zero
            for (int bit = 0; bit < 32; ++bit) {
                const int j = j0 + bit;
                if (j > i) {
                    float il = fmaxf(li, sL[j]);
                    float it = fmaxf(ti, sT[j]);
                    float ir = fminf(ri, sR[j]);
                    float ib = fminf(bi, sD[j]);
                    float iw = ir - il, ih = ib - it;
                    if (iw > 0.0f && ih > 0.0f) {
                        float inter = iw * ih;
                        float aj    = sA[j];
                        float d     = 2.0f * inter;
                        bool sup;
                        if      (d < aj * 0.99999f) sup = false;  // ratio clearly < 0.5
                        else if (d > aj * 1.00001f) sup = true;   // ratio clearly >= 0.5
                        else sup = !((inter / aj) < 0.5f);        // exact ref semantics
                        if (sup) word |= (1u << bit);
                    }
                }
            }
        }
        Mrow[w] = word;
    }
}

// ---------------------------------------------------------------------------
// Kernel C: serial greedy walk, one wave per batch. Lane L owns keep bits for
// j in [32L, 32L+32). Early exit once 100 boxes are kept. Writes all 100
// output slots (zeros past kept count).
// ---------------------------------------------------------------------------
__global__ __launch_bounds__(64) void nms_walk(const uint32_t* __restrict__ M,
                                               const float4* __restrict__ sortedBox,
                                               float* __restrict__ out) {
    __shared__ int slots[NR];
    const int b    = blockIdx.x;
    const int lane = threadIdx.x;
    const uint32_t* Mb = M + (size_t)b * NN * NW;

    uint32_t keep = 0xFFFFFFFFu;
    int count = 0;

    for (int i0 = 0; i0 < NN; i0 += 8) {
        uint32_t rr[8];
#pragma unroll
        for (int k = 0; k < 8; ++k)        // 8 independent loads in flight
            rr[k] = Mb[(size_t)(i0 + k) * NW + lane];
#pragma unroll
        for (int k = 0; k < 8; ++k) {
            const int i = i0 + k;
            uint32_t kw = __shfl(keep, i >> 5);
            if ((kw >> (i & 31)) & 1u) {   // box i survives -> suppress its row
                keep &= ~rr[k];
                if (lane == 0 && count < NR) slots[count] = i;
                ++count;
            }
        }
        if (count >= NR) break;            // first 100 kept are final
    }
    __syncthreads();

    for (int s = lane; s < NR; s += 64) {
        float x = 0.f, y = 0.f, z = 0.f;
        if (s < count) {
            float4 q = sortedBox[(size_t)b * NN + slots[s]];
            x = q.y; y = q.z; z = q.w;     // vals = (top, right, bottom)
        }
        float* o = out + ((size_t)b * NR + s) * 3;
        o[0] = x; o[1] = y; o[2] = z;
    }
}

// ---------------------------------------------------------------------------
extern "C" void kernel_launch(void* const* d_in, const int* in_sizes, int n_in,
                              void* d_out, int out_size, void* d_ws, size_t ws_size,
                              hipStream_t stream) {
    const float* pred = (const float*)d_in[0];
    float* out = (float*)d_out;
    char* ws = (char*)d_ws;

    float4*   sortedBox = (float4*)ws;                                   // 1 MB
    uint32_t* M         = (uint32_t*)(ws + (size_t)NB * NN * sizeof(float4)); // 16 MB

    nms_sort <<<NB, 1024, 0, stream>>>(pred, sortedBox);
    nms_pairs<<<dim3(16, NB), 256, 0, stream>>>(sortedBox, M);
    nms_walk <<<NB, 64, 0, stream>>>(M, sortedBox, out);
}

// Round 2
// 124.705 us; speedup vs baseline: 1.6505x; 1.6505x over previous
//
#include <hip/hip_runtime.h>
#include <stdint.h>

#define NB 32
#define NN 2048
#define NR 100
#define NW 64   // 2048 bits / 32 = 64 u32 words per suppression row
#define IC 256  // i-chunk (rows) per block
#define JC 256  // j-span per block = 4 waves x 64 lanes

__device__ __forceinline__ uint32_t ordered_f32(float f) {
    uint32_t u = __float_as_uint(f);
    return (u & 0x80000000u) ? ~u : (u | 0x80000000u);
}

// ---------------------------------------------------------------------------
// Kernel A: per-batch stable sort by descending score.
// Key = (~ordered(score) << 32) | index, ascending bitonic sort in LDS.
// ---------------------------------------------------------------------------
__global__ __launch_bounds__(1024) void nms_sort(const float* __restrict__ pred,
                                                 float4* __restrict__ sortedBox) {
    __shared__ uint64_t sk[NN];
    const int b   = blockIdx.x;
    const int tid = threadIdx.x;
    const float* p = pred + (size_t)b * NN * 5;

    for (int i = tid; i < NN; i += 1024) {
        float sc = p[i * 5 + 0];
        uint32_t k32 = ~ordered_f32(sc);           // ascending key == descending score
        sk[i] = ((uint64_t)k32 << 32) | (uint32_t)i;
    }
    __syncthreads();

    for (int k = 2; k <= NN; k <<= 1) {
        for (int j = k >> 1; j > 0; j >>= 1) {
            for (int i = tid; i < NN; i += 1024) {
                int ixj = i ^ j;
                if (ixj > i) {
                    uint64_t a = sk[i], c = sk[ixj];
                    bool up = ((i & k) == 0);
                    if ((a > c) == up) { sk[i] = c; sk[ixj] = a; }
                }
            }
            __syncthreads();
        }
    }

    for (int s = tid; s < NN; s += 1024) {
        int idx = (int)(uint32_t)sk[s];
        const float* q = p + idx * 5;
        sortedBox[(size_t)b * NN + s] = make_float4(q[1], q[2], q[3], q[4]);
    }
}

// ---------------------------------------------------------------------------
// Kernel B: suppression bit matrix, upper triangle only.
// Lane owns column j (box in registers); rows i broadcast from LDS.
// 64 pair tests per wave-iteration -> one __ballot -> one 8B store (lane 0).
// Exact ref semantics via double compare: RN(inter/aj) >= 0.5
//   <=> inter >= aj*(0.5 - 2^-26)  (RHS exact in double: 24+25 bits).
// Word-pair p of row i is written iff i < 64p+64; walk masks the rest.
// ---------------------------------------------------------------------------
__global__ __launch_bounds__(256) void nms_pairs(const float4* __restrict__ sortedBox,
                                                 uint32_t* __restrict__ M) {
    __shared__ float4 sBox[IC];
    const int b  = blockIdx.z;
    const int jy = blockIdx.y;
    const int ix = blockIdx.x;
    const int ibase = ix * IC;
    if (ibase >= jy * JC + JC) return;             // block entirely lower-triangle

    const int tid = threadIdx.x;
    const float4* box = sortedBox + (size_t)b * NN;

    sBox[tid] = box[ibase + tid];                  // stage i-chunk (4KB)
    __syncthreads();

    const int wave  = tid >> 6;
    const int lane  = tid & 63;
    const int jbase = jy * JC + wave * 64;
    const int j     = jbase + lane;

    const float4 bj = box[j];
    const float  aj = (bj.z - bj.x) * (bj.w - bj.y);
    const double ajC = (double)aj * (0.5 - 0x1p-26);

    uint32_t* Mb = M + (size_t)b * NN * NW;

    int i = ibase;
    const int iend_full = min(ibase + IC, jbase);  // i < jbase: every j > i
#pragma unroll 4
    for (; i < iend_full; ++i) {
        float4 bi = sBox[i - ibase];
        float il = fmaxf(bi.x, bj.x);
        float it = fmaxf(bi.y, bj.y);
        float ir = fminf(bi.z, bj.z);
        float ib = fminf(bi.w, bj.w);
        float inter = fmaxf(ir - il, 0.0f) * fmaxf(ib - it, 0.0f);
        uint64_t m = __ballot((double)inter >= ajC);
        if (lane == 0)
            *(uint64_t*)(Mb + (size_t)i * NW + (jbase >> 5)) = m;
    }
    const int mend = min(ibase + IC, jbase + 64);  // masked band: i in [jbase, jbase+64)
    for (; i < mend; ++i) {
        float4 bi = sBox[i - ibase];
        float il = fmaxf(bi.x, bj.x);
        float it = fmaxf(bi.y, bj.y);
        float ir = fminf(bi.z, bj.z);
        float ib = fminf(bi.w, bj.w);
        float inter = fmaxf(ir - il, 0.0f) * fmaxf(ib - it, 0.0f);
        uint64_t m = __ballot(((double)inter >= ajC) && (j > i));
        if (lane == 0)
            *(uint64_t*)(Mb + (size_t)i * NW + (jbase >> 5)) = m;
    }
}

// ---------------------------------------------------------------------------
// Kernel C: serial greedy walk, one wave per batch. Lane L owns keep bits for
// j in [32L, 32L+32). Word-pair p of row i is valid only if p >= i>>6
// (lower-triangle pairs were never written). Early exit at 100 kept.
// ---------------------------------------------------------------------------
__global__ __launch_bounds__(64) void nms_walk(const uint32_t* __restrict__ M,
                                               const float4* __restrict__ sortedBox,
                                               float* __restrict__ out) {
    __shared__ int slots[NR];
    const int b    = blockIdx.x;
    const int lane = threadIdx.x;
    const uint32_t* Mb = M + (size_t)b * NN * NW;

    uint32_t keep = 0xFFFFFFFFu;
    int count = 0;

    for (int i0 = 0; i0 < NN; i0 += 8) {
        uint32_t rr[8];
#pragma unroll
        for (int k = 0; k < 8; ++k)                // 8 independent loads in flight
            rr[k] = Mb[(size_t)(i0 + k) * NW + lane];
#pragma unroll
        for (int k = 0; k < 8; ++k) {
            const int i = i0 + k;
            uint32_t kw = __shfl(keep, i >> 5);
            if ((kw >> (i & 31)) & 1u) {           // box i survives -> suppress its row
                uint32_t vm = ((lane >> 1) >= (i >> 6)) ? rr[k] : 0u;
                keep &= ~vm;
                if (lane == 0 && count < NR) slots[count] = i;
                ++count;
            }
        }
        if (count >= NR) break;                    // first 100 kept are final
    }
    __syncthreads();

    for (int s = lane; s < NR; s += 64) {
        float x = 0.f, y = 0.f, z = 0.f;
        if (s < count) {
            float4 q = sortedBox[(size_t)b * NN + slots[s]];
            x = q.y; y = q.z; z = q.w;             // vals = (top, right, bottom)
        }
        float* o = out + ((size_t)b * NR + s) * 3;
        o[0] = x; o[1] = y; o[2] = z;
    }
}

// ---------------------------------------------------------------------------
extern "C" void kernel_launch(void* const* d_in, const int* in_sizes, int n_in,
                              void* d_out, int out_size, void* d_ws, size_t ws_size,
                              hipStream_t stream) {
    const float* pred = (const float*)d_in[0];
    float* out = (float*)d_out;
    char* ws = (char*)d_ws;

    float4*   sortedBox = (float4*)ws;                                        // 1 MB
    uint32_t* M         = (uint32_t*)(ws + (size_t)NB * NN * sizeof(float4)); // 16 MB

    nms_sort <<<NB, 1024, 0, stream>>>(pred, sortedBox);
    nms_pairs<<<dim3(NN / IC, NN / JC, NB), 256, 0, stream>>>(sortedBox, M);
    nms_walk <<<NB, 64, 0, stream>>>(M, sortedBox, out);
}

// Round 3
// 85.212 us; speedup vs baseline: 2.4154x; 1.4635x over previous
//
#include <hip/hip_runtime.h>
#include <stdint.h>

#define NB 32
#define NN 2048
#define NR 100
#define NW 64     // u32 words per suppression row
#define NW64 32   // u64 words per suppression row

__device__ __forceinline__ uint32_t ordered_f32(float f) {
    uint32_t u = __float_as_uint(f);
    return (u & 0x80000000u) ? ~u : (u | 0x80000000u);
}

// ---------------------------------------------------------------------------
// Kernel A: per-batch stable sort by descending score.
// Key = (~ordered(score) << 32) | index, ascending bitonic sort in LDS.
// ---------------------------------------------------------------------------
__global__ __launch_bounds__(1024) void nms_sort(const float* __restrict__ pred,
                                                 float4* __restrict__ sortedBox) {
    __shared__ uint64_t sk[NN];
    const int b   = blockIdx.x;
    const int tid = threadIdx.x;
    const float* p = pred + (size_t)b * NN * 5;

    for (int i = tid; i < NN; i += 1024) {
        float sc = p[i * 5 + 0];
        uint32_t k32 = ~ordered_f32(sc);           // ascending key == descending score
        sk[i] = ((uint64_t)k32 << 32) | (uint32_t)i;
    }
    __syncthreads();

    for (int k = 2; k <= NN; k <<= 1) {
        for (int j = k >> 1; j > 0; j >>= 1) {
            for (int i = tid; i < NN; i += 1024) {
                int ixj = i ^ j;
                if (ixj > i) {
                    uint64_t a = sk[i], c = sk[ixj];
                    bool up = ((i & k) == 0);
                    if ((a > c) == up) { sk[i] = c; sk[ixj] = a; }
                }
            }
            __syncthreads();
        }
    }

    for (int s = tid; s < NN; s += 1024) {
        int idx = (int)(uint32_t)sk[s];
        const float* q = p + idx * 5;
        sortedBox[(size_t)b * NN + s] = make_float4(q[1], q[2], q[3], q[4]);
    }
}

// ---------------------------------------------------------------------------
// Kernel B: suppression bit matrix, upper triangle only, pure-VALU inner loop.
// Tile = 64 rows x 256 cols; only upper-tri tiles launched (144 per batch).
// Lane owns column j (box in registers); rows i come from the SCALAR path
// (uniform s_load_dwordx4 via K$). Row-k ballot accumulates into lane k's
// register; one 8B store per lane at the end (row i0+lane, word-pair p).
// Exact ref semantics: RN(inter/aj) >= 0.5  <=>  inter >= 0.5f*aj, because
// the true threshold c - c*2^-25 lies strictly in (pred(c), c) and no f32
// value exists there (c = 0.5*aj exact: areas are normal).
// Word-pair p of row i is written iff p >= i>>6; walk masks the rest.
// ---------------------------------------------------------------------------
__global__ __launch_bounds__(256) void nms_pairs(const float4* __restrict__ sortedBox,
                                                 uint64_t* __restrict__ M) {
    const int b  = blockIdx.y;
    const int bx = blockIdx.x;
    int jt = 0;                             // decode upper-tri tile list:
    while (2 * (jt + 1) * (jt + 2) <= bx) ++jt;   // prefix P(jt) = 2*jt*(jt+1)
    const int it = bx - 2 * jt * (jt + 1);  // it in [0, 4*jt+4)

    const int wave = threadIdx.x >> 6;
    const int lane = threadIdx.x & 63;
    const int p    = jt * 4 + wave;         // u64 word index within the row
    if (p < it) return;                     // whole word below diagonal

    const float4* box = sortedBox + (size_t)b * NN;
    const int j  = jt * 256 + wave * 64 + lane;
    const int i0 = it * 64;

    const float4 bj = box[j];
    const float  c  = 0.5f * ((bj.z - bj.x) * (bj.w - bj.y));

    const float4* bp = box + i0;            // uniform -> scalar loads
    uint64_t word = 0;

    if (p > it) {                           // strictly above diagonal: no j>i test
#pragma unroll 16
        for (int k = 0; k < 64; ++k) {
            float4 bi = bp[k];
            float il = fmaxf(bi.x, bj.x);
            float iy = fmaxf(bi.y, bj.y);
            float ir = fminf(bi.z, bj.z);
            float ib = fminf(bi.w, bj.w);
            float inter = fmaxf(ir - il, 0.0f) * fmaxf(ib - iy, 0.0f);
            uint64_t m = __ballot(inter >= c);
            word = (lane == k) ? m : word;
        }
    } else {                                // diagonal word-pair: mask j > i
#pragma unroll 16
        for (int k = 0; k < 64; ++k) {
            float4 bi = bp[k];
            float il = fmaxf(bi.x, bj.x);
            float iy = fmaxf(bi.y, bj.y);
            float ir = fminf(bi.z, bj.z);
            float ib = fminf(bi.w, bj.w);
            float inter = fmaxf(ir - il, 0.0f) * fmaxf(ib - iy, 0.0f);
            uint64_t m = __ballot((inter >= c) && (j > i0 + k));
            word = (lane == k) ? m : word;
        }
    }
    M[((size_t)b * NN + i0 + lane) * NW64 + p] = word;
}

// ---------------------------------------------------------------------------
// Kernel C: serial greedy walk, one wave per batch. Lane L owns keep bits for
// j in [32L, 32L+32). Word-pair p of row i is valid only if p >= i>>6
// (lower-triangle words were never written). Early exit at 100 kept.
// ---------------------------------------------------------------------------
__global__ __launch_bounds__(64) void nms_walk(const uint32_t* __restrict__ M,
                                               const float4* __restrict__ sortedBox,
                                               float* __restrict__ out) {
    __shared__ int slots[NR];
    const int b    = blockIdx.x;
    const int lane = threadIdx.x;
    const uint32_t* Mb = M + (size_t)b * NN * NW;

    uint32_t keep = 0xFFFFFFFFu;
    int count = 0;

    for (int i0 = 0; i0 < NN; i0 += 8) {
        uint32_t rr[8];
#pragma unroll
        for (int k = 0; k < 8; ++k)                // 8 independent loads in flight
            rr[k] = Mb[(size_t)(i0 + k) * NW + lane];
#pragma unroll
        for (int k = 0; k < 8; ++k) {
            const int i = i0 + k;
            uint32_t kw = __shfl(keep, i >> 5);
            if ((kw >> (i & 31)) & 1u) {           // box i survives -> suppress its row
                uint32_t vm = ((lane >> 1) >= (i >> 6)) ? rr[k] : 0u;
                keep &= ~vm;
                if (lane == 0 && count < NR) slots[count] = i;
                ++count;
            }
        }
        if (count >= NR) break;                    // first 100 kept are final
    }
    __syncthreads();

    for (int s = lane; s < NR; s += 64) {
        float x = 0.f, y = 0.f, z = 0.f;
        if (s < count) {
            float4 q = sortedBox[(size_t)b * NN + slots[s]];
            x = q.y; y = q.z; z = q.w;             // vals = (top, right, bottom)
        }
        float* o = out + ((size_t)b * NR + s) * 3;
        o[0] = x; o[1] = y; o[2] = z;
    }
}

// ---------------------------------------------------------------------------
extern "C" void kernel_launch(void* const* d_in, const int* in_sizes, int n_in,
                              void* d_out, int out_size, void* d_ws, size_t ws_size,
                              hipStream_t stream) {
    const float* pred = (const float*)d_in[0];
    float* out = (float*)d_out;
    char* ws = (char*)d_ws;

    float4*   sortedBox = (float4*)ws;                                        // 1 MB
    uint64_t* M         = (uint64_t*)(ws + (size_t)NB * NN * sizeof(float4)); // 16 MB

    nms_sort <<<NB, 1024, 0, stream>>>(pred, sortedBox);
    nms_pairs<<<dim3(144, NB), 256, 0, stream>>>(sortedBox, M);
    nms_walk <<<NB, 64, 0, stream>>>((const uint32_t*)M, sortedBox, out);
}

// Round 4
// 61.088 us; speedup vs baseline: 3.3693x; 1.3949x over previous
//
#include <hip/hip_runtime.h>
#include <stdint.h>

#define NB 32
#define NN 2048
#define NR 100
#define NW 64      // u32 words per suppression row
#define NW64 32    // u64 words per suppression row
#define ROWCAP 384 // precomputed suppression rows (walk has exact fallback past this)

__device__ __forceinline__ uint32_t ordered_f32(float f) {
    uint32_t u = __float_as_uint(f);
    return (u & 0x80000000u) ? ~u : (u | 0x80000000u);
}

// ---------------------------------------------------------------------------
// Kernel A: rank-by-counting sort (stable, exact). Key = (~ord(score)<<32)|i,
// all keys distinct -> rank = #{j: key_j < key_i} is the exact permutation of
// jnp.argsort(-scores) (descending score, index-ascending ties). No barriers
// in the O(N^2) part; inner loop = uniform ds_read_b128 (2 keys) + 2 cmp+add.
// 8 blocks x 256 thr per batch; scatters sorted boxes as float4.
// ---------------------------------------------------------------------------
__global__ __launch_bounds__(256) void nms_rank(const float* __restrict__ pred,
                                                float4* __restrict__ sortedBox) {
    __shared__ uint64_t keys[NN];          // 16 KB
    const int b     = blockIdx.y;
    const int chunk = blockIdx.x;          // 8 chunks of 256 boxes
    const int tid   = threadIdx.x;
    const float* p  = pred + (size_t)b * NN * 5;

    for (int i = tid; i < NN; i += 256) {
        float sc = p[i * 5 + 0];
        keys[i] = ((uint64_t)(~ordered_f32(sc)) << 32) | (uint32_t)i;
    }
    __syncthreads();

    const int i = chunk * 256 + tid;
    const uint64_t myk = keys[i];
    const ulonglong2* k2 = (const ulonglong2*)keys;
    int rank = 0;
#pragma unroll 8
    for (int j = 0; j < NN / 2; ++j) {     // wave-uniform broadcast reads
        ulonglong2 kk = k2[j];
        rank += (kk.x < myk) + (kk.y < myk);
    }

    float4 v = make_float4(p[i * 5 + 1], p[i * 5 + 2], p[i * 5 + 3], p[i * 5 + 4]);
    sortedBox[(size_t)b * NN + rank] = v;
}

// ---------------------------------------------------------------------------
// Kernel B: suppression bit matrix, rows < ROWCAP only, upper triangle only.
// Tile = 64 rows x 256 cols. Lane owns column j (box in registers); rows via
// the scalar path (uniform loads through K$). Row-k ballot accumulates into
// lane k's register; one 8B store per lane at the end.
// Exact ref semantics: RN(inter/aj) >= 0.5  <=>  inter >= 0.5f*aj (the true
// threshold c - c*2^-25 lies in (pred(c), c); no f32 exists there).
// Word-pair p of row i is written iff p >= i>>6; walk masks the rest.
// Tiles per batch: jt=0 -> it in [0,4); jt>=1 -> it in [0,6). Total 46.
// ---------------------------------------------------------------------------
__global__ __launch_bounds__(256) void nms_pairs(const float4* __restrict__ sortedBox,
                                                 uint64_t* __restrict__ M) {
    const int b  = blockIdx.y;
    const int bx = blockIdx.x;
    int jt, it;
    if (bx < 4) { jt = 0; it = bx; }
    else        { int t = bx - 4; jt = 1 + t / 6; it = t - (jt - 1) * 6; }

    const int wave = threadIdx.x >> 6;
    const int lane = threadIdx.x & 63;
    const int p    = jt * 4 + wave;        // u64 word index within the row
    if (p < it) return;                    // whole word below diagonal

    const float4* box = sortedBox + (size_t)b * NN;
    const int j  = jt * 256 + wave * 64 + lane;
    const int i0 = it * 64;

    const float4 bj = box[j];
    const float  c  = 0.5f * ((bj.z - bj.x) * (bj.w - bj.y));

    const float4* bp = box + i0;           // uniform -> scalar loads
    uint64_t word = 0;

    if (p > it) {                          // strictly above diagonal: no j>i test
#pragma unroll 16
        for (int k = 0; k < 64; ++k) {
            float4 bi = bp[k];
            float il = fmaxf(bi.x, bj.x);
            float iy = fmaxf(bi.y, bj.y);
            float ir = fminf(bi.z, bj.z);
            float ib = fminf(bi.w, bj.w);
            float inter = fmaxf(ir - il, 0.0f) * fmaxf(ib - iy, 0.0f);
            uint64_t m = __ballot(inter >= c);
            word = (lane == k) ? m : word;
        }
    } else {                               // diagonal word-pair: mask j > i
#pragma unroll 16
        for (int k = 0; k < 64; ++k) {
            float4 bi = bp[k];
            float il = fmaxf(bi.x, bj.x);
            float iy = fmaxf(bi.y, bj.y);
            float ir = fminf(bi.z, bj.z);
            float ib = fminf(bi.w, bj.w);
            float inter = fmaxf(ir - il, 0.0f) * fmaxf(ib - iy, 0.0f);
            uint64_t m = __ballot((inter >= c) && (j > i0 + k));
            word = (lane == k) ? m : word;
        }
    }
    M[((size_t)b * NN + i0 + lane) * NW64 + p] = word;
}

// ---------------------------------------------------------------------------
// Kernel C: serial greedy walk, one wave per batch. Lane L owns keep bits for
// j in [32L, 32L+32). Word-pair p of row i valid only if p >= i>>6. Early
// exit at 100 kept. If 100 not reached by ROWCAP (pathological inputs only),
// computes remaining rows' suppression on the fly with identical semantics.
// ---------------------------------------------------------------------------
__global__ __launch_bounds__(64) void nms_walk(const uint32_t* __restrict__ M,
                                               const float4* __restrict__ sortedBox,
                                               float* __restrict__ out) {
    __shared__ int slots[NR];
    const int b    = blockIdx.x;
    const int lane = threadIdx.x;
    const uint32_t* Mb = M + (size_t)b * NN * NW;
    const float4* box  = sortedBox + (size_t)b * NN;

    uint32_t keep = 0xFFFFFFFFu;
    int count = 0;

    for (int i0 = 0; i0 < ROWCAP; i0 += 8) {
        uint32_t rr[8];
#pragma unroll
        for (int k = 0; k < 8; ++k)                // 8 independent loads in flight
            rr[k] = Mb[(size_t)(i0 + k) * NW + lane];
#pragma unroll
        for (int k = 0; k < 8; ++k) {
            const int i = i0 + k;
            uint32_t kw = __shfl(keep, i >> 5);
            if ((kw >> (i & 31)) & 1u) {           // box i survives -> suppress row
                uint32_t vm = ((lane >> 1) >= (i >> 6)) ? rr[k] : 0u;
                keep &= ~vm;
                if (lane == 0 && count < NR) slots[count] = i;
                ++count;
            }
        }
        if (count >= NR) break;                    // first 100 kept are final
    }

    // Fallback (correctness only; not expected to execute for this input).
    if (count < NR) {
        for (int i = ROWCAP; i < NN && count < NR; ++i) {
            uint32_t kw = __shfl(keep, i >> 5);
            if ((kw >> (i & 31)) & 1u) {
                float4 bi = box[i];                // wave-uniform broadcast
                uint32_t kill = 0;
                for (int t = 0; t < 32; ++t) {
                    int j = lane * 32 + t;
                    if (j > i) {
                        float4 bj = box[j];
                        float c  = 0.5f * ((bj.z - bj.x) * (bj.w - bj.y));
                        float il = fmaxf(bi.x, bj.x);
                        float iy = fmaxf(bi.y, bj.y);
                        float ir = fminf(bi.z, bj.z);
                        float ib = fminf(bi.w, bj.w);
                        float inter = fmaxf(ir - il, 0.0f) * fmaxf(ib - iy, 0.0f);
                        if (inter >= c) kill |= (1u << t);
                    }
                }
                keep &= ~kill;
                if (lane == 0 && count < NR) slots[count] = i;
                ++count;
            }
        }
    }
    __syncthreads();

    for (int s = lane; s < NR; s += 64) {
        float x = 0.f, y = 0.f, z = 0.f;
        if (s < count) {
            float4 q = box[slots[s]];
            x = q.y; y = q.z; z = q.w;             // vals = (top, right, bottom)
        }
        float* o = out + ((size_t)b * NR + s) * 3;
        o[0] = x; o[1] = y; o[2] = z;
    }
}

// ---------------------------------------------------------------------------
extern "C" void kernel_launch(void* const* d_in, const int* in_sizes, int n_in,
                              void* d_out, int out_size, void* d_ws, size_t ws_size,
                              hipStream_t stream) {
    const float* pred = (const float*)d_in[0];
    float* out = (float*)d_out;
    char* ws = (char*)d_ws;

    float4*   sortedBox = (float4*)ws;                                        // 1 MB
    uint64_t* M         = (uint64_t*)(ws + (size_t)NB * NN * sizeof(float4)); // 3 MB used

    nms_rank <<<dim3(8, NB), 256, 0, stream>>>(pred, sortedBox);
    nms_pairs<<<dim3(46, NB), 256, 0, stream>>>(sortedBox, M);
    nms_walk <<<NB, 64, 0, stream>>>((const uint32_t*)M, sortedBox, out);
}

// Round 5
// 44.833 us; speedup vs baseline: 4.5909x; 1.3626x over previous
//
#include <hip/hip_runtime.h>
#include <stdint.h>

#define NB 32
#define NN 2048
#define NR 100
#define NW 64      // u32 words per suppression row
#define NW64 32    // u64 words per suppression row
#define ROWCAP 256 // precomputed suppression rows (walk has exact fallback past this)

__device__ __forceinline__ uint32_t ordered_f32(float f) {
    uint32_t u = __float_as_uint(f);
    return (u & 0x80000000u) ? ~u : (u | 0x80000000u);
}

// ---------------------------------------------------------------------------
// Kernel A: rank-by-counting sort (stable, exact). Key = (~ord(score)<<32)|i,
// all keys distinct -> rank = #{j: key_j < key_i} is the exact permutation of
// jnp.argsort(-scores). 4-way split-scan: 1024 threads/block, 4 threads per
// box each scanning a 512-key LDS segment (wave-uniform b128 broadcasts),
// partials combined via LDS. 4 waves/SIMD hides the LDS dependent-chain
// latency that bound the previous 1-wave/SIMD version.
// ---------------------------------------------------------------------------
__global__ __launch_bounds__(1024) void nms_rank(const float* __restrict__ pred,
                                                 float4* __restrict__ sortedBox) {
    __shared__ uint64_t keys[NN];          // 16 KB
    __shared__ int      psum[4][256];      // 4 KB
    const int b     = blockIdx.y;
    const int chunk = blockIdx.x;          // 8 chunks of 256 boxes
    const int tid   = threadIdx.x;
    const float* p  = pred + (size_t)b * NN * 5;

    for (int i = tid; i < NN; i += 1024) {
        float sc = p[i * 5 + 0];
        keys[i] = ((uint64_t)(~ordered_f32(sc)) << 32) | (uint32_t)i;
    }
    __syncthreads();

    const int boxL = tid & 255;            // local box id within chunk
    const int seg  = tid >> 8;             // 4 segments x 512 keys
    const uint64_t myk = keys[chunk * 256 + boxL];
    const ulonglong2* k2 = (const ulonglong2*)keys + seg * 256;

    int r = 0;
#pragma unroll 8
    for (int jj = 0; jj < 256; ++jj) {     // wave-uniform broadcast reads
        ulonglong2 kk = k2[jj];
        r += (kk.x < myk) + (kk.y < myk);
    }
    psum[seg][boxL] = r;
    __syncthreads();

    if (tid < 256) {
        int rank = psum[0][tid] + psum[1][tid] + psum[2][tid] + psum[3][tid];
        const float* q = p + (size_t)(chunk * 256 + tid) * 5;
        sortedBox[(size_t)b * NN + rank] = make_float4(q[1], q[2], q[3], q[4]);
    }
}

// ---------------------------------------------------------------------------
// Kernel B: suppression bit matrix, rows < ROWCAP only, upper triangle only.
// Tile = 64 rows x 256 cols; 32 tiles/batch (it = bx&3, jt = bx>>2).
// Lane owns column j (box in registers); rows via the scalar path (uniform
// loads through K$). Row-k ballot accumulates into lane k's register; one 8B
// store per lane at the end.
// Exact ref semantics: RN(inter/aj) >= 0.5  <=>  inter >= 0.5f*aj (the true
// threshold c - c*2^-25 lies in (pred(c), c); no f32 exists there).
// Word-pair p of row i is written iff p >= i>>6; walk masks the rest.
// ---------------------------------------------------------------------------
__global__ __launch_bounds__(256) void nms_pairs(const float4* __restrict__ sortedBox,
                                                 uint64_t* __restrict__ M) {
    const int b  = blockIdx.y;
    const int bx = blockIdx.x;
    const int jt = bx >> 2;                // j-tile: 8 x 256 cols
    const int it = bx & 3;                 // i-tile: 4 x 64 rows (ROWCAP=256)

    const int wave = threadIdx.x >> 6;
    const int lane = threadIdx.x & 63;
    const int p    = jt * 4 + wave;        // u64 word index within the row
    if (p < it) return;                    // whole word below diagonal

    const float4* box = sortedBox + (size_t)b * NN;
    const int j  = jt * 256 + wave * 64 + lane;
    const int i0 = it * 64;

    const float4 bj = box[j];
    const float  c  = 0.5f * ((bj.z - bj.x) * (bj.w - bj.y));

    const float4* bp = box + i0;           // uniform -> scalar loads
    uint64_t word = 0;

    if (p > it) {                          // strictly above diagonal: no j>i test
#pragma unroll 16
        for (int k = 0; k < 64; ++k) {
            float4 bi = bp[k];
            float il = fmaxf(bi.x, bj.x);
            float iy = fmaxf(bi.y, bj.y);
            float ir = fminf(bi.z, bj.z);
            float ib = fminf(bi.w, bj.w);
            float inter = fmaxf(ir - il, 0.0f) * fmaxf(ib - iy, 0.0f);
            uint64_t m = __ballot(inter >= c);
            word = (lane == k) ? m : word;
        }
    } else {                               // diagonal word-pair: mask j > i
#pragma unroll 16
        for (int k = 0; k < 64; ++k) {
            float4 bi = bp[k];
            float il = fmaxf(bi.x, bj.x);
            float iy = fmaxf(bi.y, bj.y);
            float ir = fminf(bi.z, bj.z);
            float ib = fminf(bi.w, bj.w);
            float inter = fmaxf(ir - il, 0.0f) * fmaxf(ib - iy, 0.0f);
            uint64_t m = __ballot((inter >= c) && (j > i0 + k));
            word = (lane == k) ? m : word;
        }
    }
    M[((size_t)b * NN + i0 + lane) * NW64 + p] = word;
}

// ---------------------------------------------------------------------------
// Kernel C: serial greedy walk, one wave per batch. Lane L owns keep bits for
// j in [32L, 32L+32). Word-pair p of row i valid only if p >= i>>6. Early
// exit at 100 kept. If 100 not reached by ROWCAP (pathological inputs only),
// computes remaining rows' suppression on the fly with identical semantics.
// ---------------------------------------------------------------------------
__global__ __launch_bounds__(64) void nms_walk(const uint32_t* __restrict__ M,
                                               const float4* __restrict__ sortedBox,
                                               float* __restrict__ out) {
    __shared__ int slots[NR];
    const int b    = blockIdx.x;
    const int lane = threadIdx.x;
    const uint32_t* Mb = M + (size_t)b * NN * NW;
    const float4* box  = sortedBox + (size_t)b * NN;

    uint32_t keep = 0xFFFFFFFFu;
    int count = 0;

    for (int i0 = 0; i0 < ROWCAP; i0 += 8) {
        uint32_t rr[8];
#pragma unroll
        for (int k = 0; k < 8; ++k)                // 8 independent loads in flight
            rr[k] = Mb[(size_t)(i0 + k) * NW + lane];
#pragma unroll
        for (int k = 0; k < 8; ++k) {
            const int i = i0 + k;
            uint32_t kw = __shfl(keep, i >> 5);
            if ((kw >> (i & 31)) & 1u) {           // box i survives -> suppress row
                uint32_t vm = ((lane >> 1) >= (i >> 6)) ? rr[k] : 0u;
                keep &= ~vm;
                if (lane == 0 && count < NR) slots[count] = i;
                ++count;
            }
        }
        if (count >= NR) break;                    // first 100 kept are final
    }

    // Fallback (correctness only; not expected to execute for this input).
    if (count < NR) {
        for (int i = ROWCAP; i < NN && count < NR; ++i) {
            uint32_t kw = __shfl(keep, i >> 5);
            if ((kw >> (i & 31)) & 1u) {
                float4 bi = box[i];                // wave-uniform broadcast
                uint32_t kill = 0;
                for (int t = 0; t < 32; ++t) {
                    int j = lane * 32 + t;
                    if (j > i) {
                        float4 bj = box[j];
                        float c  = 0.5f * ((bj.z - bj.x) * (bj.w - bj.y));
                        float il = fmaxf(bi.x, bj.x);
                        float iy = fmaxf(bi.y, bj.y);
                        float ir = fminf(bi.z, bj.z);
                        float ib = fminf(bi.w, bj.w);
                        float inter = fmaxf(ir - il, 0.0f) * fmaxf(ib - iy, 0.0f);
                        if (inter >= c) kill |= (1u << t);
                    }
                }
                keep &= ~kill;
                if (lane == 0 && count < NR) slots[count] = i;
                ++count;
            }
        }
    }
    __syncthreads();

    for (int s = lane; s < NR; s += 64) {
        float x = 0.f, y = 0.f, z = 0.f;
        if (s < count) {
            float4 q = box[slots[s]];
            x = q.y; y = q.z; z = q.w;             // vals = (top, right, bottom)
        }
        float* o = out + ((size_t)b * NR + s) * 3;
        o[0] = x; o[1] = y; o[2] = z;
    }
}

// ---------------------------------------------------------------------------
extern "C" void kernel_launch(void* const* d_in, const int* in_sizes, int n_in,
                              void* d_out, int out_size, void* d_ws, size_t ws_size,
                              hipStream_t stream) {
    const float* pred = (const float*)d_in[0];
    float* out = (float*)d_out;
    char* ws = (char*)d_ws;

    float4*   sortedBox = (float4*)ws;                                        // 1 MB
    uint64_t* M         = (uint64_t*)(ws + (size_t)NB * NN * sizeof(float4)); // 2 MB used

    nms_rank <<<dim3(8, NB), 1024, 0, stream>>>(pred, sortedBox);
    nms_pairs<<<dim3(32, NB), 256, 0, stream>>>(sortedBox, M);
    nms_walk <<<NB, 64, 0, stream>>>((const uint32_t*)M, sortedBox, out);
}

// Round 7
// 42.316 us; speedup vs baseline: 4.8639x; 1.0595x over previous
//
#include <hip/hip_runtime.h>
#include <stdint.h>

#define NB 32
#define NN 2048
#define NR 100
#define NW 64      // u32 words per suppression row
#define ROWCAP 256 // precomputed suppression rows (walk has exact fallback past this)

__device__ __forceinline__ uint32_t ordered_f32(float f) {
    uint32_t u = __float_as_uint(f);
    return (u & 0x80000000u) ? ~u : (u | 0x80000000u);
}

// ---------------------------------------------------------------------------
// Kernel A: rank-by-counting sort (stable, exact). Key = (~ord(score)<<32)|i,
// all keys distinct -> rank = #{j: key_j < key_i} is the exact permutation of
// jnp.argsort(-scores). 8-way split-scan: 1024 thr/block, 8 threads per box
// each scanning a 256-key LDS segment (wave-uniform b128 broadcasts),
// partials combined via LDS. 512 blocks -> 8 waves/SIMD.
// ---------------------------------------------------------------------------
__global__ __launch_bounds__(1024) void nms_rank(const float* __restrict__ pred,
                                                 float4* __restrict__ sortedBox) {
    __shared__ uint64_t keys[NN];          // 16 KB
    __shared__ int      psum[8][128];      // 4 KB
    const int b     = blockIdx.y;
    const int chunk = blockIdx.x;          // 16 chunks of 128 boxes
    const int tid   = threadIdx.x;
    const float* p  = pred + (size_t)b * NN * 5;

    for (int i = tid; i < NN; i += 1024) {
        float sc = p[i * 5 + 0];
        keys[i] = ((uint64_t)(~ordered_f32(sc)) << 32) | (uint32_t)i;
    }
    __syncthreads();

    const int boxL = tid & 127;            // local box id within chunk
    const int seg  = tid >> 7;             // 8 segments x 256 keys
    const uint64_t myk = keys[chunk * 128 + boxL];
    const ulonglong2* k2 = (const ulonglong2*)keys + seg * 128;

    int r = 0;
#pragma unroll 8
    for (int jj = 0; jj < 128; ++jj) {     // wave-uniform broadcast reads
        ulonglong2 kk = k2[jj];
        r += (kk.x < myk) + (kk.y < myk);
    }
    psum[seg][boxL] = r;
    __syncthreads();

    if (tid < 128) {
        int rank = psum[0][tid] + psum[1][tid] + psum[2][tid] + psum[3][tid]
                 + psum[4][tid] + psum[5][tid] + psum[6][tid] + psum[7][tid];
        const float* q = p + (size_t)(chunk * 128 + tid) * 5;
        sortedBox[(size_t)b * NN + rank] = make_float4(q[1], q[2], q[3], q[4]);
    }
}

// ---------------------------------------------------------------------------
// Kernel B: suppression bit matrix, rows < ROWCAP only, upper triangle only.
// Wave-tile = 64 rows x 32 cols; lane = row (box in 4 VGPRs). Col boxes and
// c_j = 0.5f*area_j staged in LDS per block (128 cols, 2.5 KB) and streamed
// as wave-uniform broadcasts. Bit k set in place (cndmask(1<<k)+or, 2 VALU).
// No ballot, no cross-lane, stores already row-major (1 u32 per lane).
// Exact ref semantics: RN(inter/aj) >= 0.5  <=>  inter >= 0.5f*aj (the true
// threshold c - c*2^-25 lies in (pred(c), c); no f32 exists there).
// Word ct of row i is written iff ct >= 2*(i>>6)  (== walk's validity mask
// (lane>>1) >= (i>>6)); diagonal-overlap bits masked at write.
// ---------------------------------------------------------------------------
__global__ __launch_bounds__(256) void nms_pairs(const float4* __restrict__ sortedBox,
                                                 uint32_t* __restrict__ M) {
    __shared__ float4 sCol[128];
    __shared__ float  sC[128];
    const int b  = blockIdx.z;
    const int rt = blockIdx.y;             // row tile: 4 x 64 rows (ROWCAP=256)
    const int cg = blockIdx.x;             // col group: 16 x 128 cols
    const int tid  = threadIdx.x;
    const int wave = tid >> 6;
    const int lane = tid & 63;

    if (cg * 4 + 3 < 2 * rt) return;       // whole block below diagonal band

    const float4* box = sortedBox + (size_t)b * NN;

    if (tid < 128) {                       // stage 128 col boxes + thresholds
        float4 v = box[cg * 128 + tid];
        sCol[tid] = v;
        sC[tid]   = 0.5f * ((v.z - v.x) * (v.w - v.y));
    }
    __syncthreads();

    const int ct = cg * 4 + wave;          // col tile: 32 cols
    if (ct < 2 * rt) return;               // wave below diagonal band

    const int i = rt * 64 + lane;          // this lane's row
    const float4 bi = box[i];              // per-lane row box

    uint32_t rowword = 0;
    const int kbase = (wave & 3) * 32;
#pragma unroll
    for (int k = 0; k < 32; ++k) {
        float4 cb = sCol[kbase + k];       // wave-uniform broadcast
        float  c  = sC[kbase + k];
        float il = fmaxf(bi.x, cb.x);
        float iy = fmaxf(bi.y, cb.y);
        float ir = fminf(bi.z, cb.z);
        float ib = fminf(bi.w, cb.w);
        float inter = fmaxf(ir - il, 0.0f) * fmaxf(ib - iy, 0.0f);
        rowword |= (inter >= c) ? (1u << k) : 0u;   // bit k = col 32ct+k
    }

    const int d = i - ct * 32;             // mask cols j <= i (diagonal tiles)
    uint32_t um = (d < 0) ? 0xFFFFFFFFu : ((d >= 31) ? 0u : (0xFFFFFFFFu << (d + 1)));
    rowword &= um;

    M[((size_t)b * NN + i) * NW + ct] = rowword;
}

// ---------------------------------------------------------------------------
// Kernel C: serial greedy walk, one wave per batch. Lane L owns keep bits for
// j in [32L, 32L+32). Word L of row i valid only if (L>>1) >= (i>>6). Early
// exit at 100 kept. If 100 not reached by ROWCAP (pathological inputs only),
// computes remaining rows' suppression on the fly with identical semantics.
// ---------------------------------------------------------------------------
__global__ __launch_bounds__(64) void nms_walk(const uint32_t* __restrict__ M,
                                               const float4* __restrict__ sortedBox,
                                               float* __restrict__ out) {
    __shared__ int slots[NR];
    const int b    = blockIdx.x;
    const int lane = threadIdx.x;
    const uint32_t* Mb = M + (size_t)b * NN * NW;
    const float4* box  = sortedBox + (size_t)b * NN;

    uint32_t keep = 0xFFFFFFFFu;
    int count = 0;

    for (int i0 = 0; i0 < ROWCAP; i0 += 8) {
        uint32_t rr[8];
#pragma unroll
        for (int k = 0; k < 8; ++k)                // 8 independent loads in flight
            rr[k] = Mb[(size_t)(i0 + k) * NW + lane];
#pragma unroll
        for (int k = 0; k < 8; ++k) {
            const int i = i0 + k;
            uint32_t kw = __shfl(keep, i >> 5);
            if ((kw >> (i & 31)) & 1u) {           // box i survives -> suppress row
                uint32_t vm = ((lane >> 1) >= (i >> 6)) ? rr[k] : 0u;
                keep &= ~vm;
                if (lane == 0 && count < NR) slots[count] = i;
                ++count;
            }
        }
        if (count >= NR) break;                    // first 100 kept are final
    }

    // Fallback (correctness only; not expected to execute for this input).
    if (count < NR) {
        for (int i = ROWCAP; i < NN && count < NR; ++i) {
            uint32_t kw = __shfl(keep, i >> 5);
            if ((kw >> (i & 31)) & 1u) {
                float4 bi = box[i];                // wave-uniform broadcast
                uint32_t kill = 0;
                for (int t = 0; t < 32; ++t) {
                    int j = lane * 32 + t;
                    if (j > i) {
                        float4 bj = box[j];
                        float c  = 0.5f * ((bj.z - bj.x) * (bj.w - bj.y));
                        float il = fmaxf(bi.x, bj.x);
                        float iy = fmaxf(bi.y, bj.y);
                        float ir = fminf(bi.z, bj.z);
                        float ib = fminf(bi.w, bj.w);
                        float inter = fmaxf(ir - il, 0.0f) * fmaxf(ib - iy, 0.0f);
                        if (inter >= c) kill |= (1u << t);
                    }
                }
                keep &= ~kill;
                if (lane == 0 && count < NR) slots[count] = i;
                ++count;
            }
        }
    }
    __syncthreads();

    for (int s = lane; s < NR; s += 64) {
        float x = 0.f, y = 0.f, z = 0.f;
        if (s < count) {
            float4 q = box[slots[s]];
            x = q.y; y = q.z; z = q.w;             // vals = (top, right, bottom)
        }
        float* o = out + ((size_t)b * NR + s) * 3;
        o[0] = x; o[1] = y; o[2] = z;
    }
}

// ---------------------------------------------------------------------------
extern "C" void kernel_launch(void* const* d_in, const int* in_sizes, int n_in,
                              void* d_out, int out_size, void* d_ws, size_t ws_size,
                              hipStream_t stream) {
    const float* pred = (const float*)d_in[0];
    float* out = (float*)d_out;
    char* ws = (char*)d_ws;

    float4*   sortedBox = (float4*)ws;                                        // 1 MB
    uint32_t* M         = (uint32_t*)(ws + (size_t)NB * NN * sizeof(float4)); // 2 MB used

    nms_rank <<<dim3(16, NB), 1024, 0, stream>>>(pred, sortedBox);
    nms_pairs<<<dim3(16, 4, NB), 256, 0, stream>>>(sortedBox, M);
    nms_walk <<<NB, 64, 0, stream>>>(M, sortedBox, out);
}

// Round 8
// 41.445 us; speedup vs baseline: 4.9661x; 1.0210x over previous
//
#include <hip/hip_runtime.h>
#include <stdint.h>

#define NB 32
#define NN 2048
#define NR 100
#define NW 64      // u32 words per suppression row
#define ROWCAP 256 // precomputed suppression rows (walk has exact fallback past this)

__device__ __forceinline__ uint32_t ordered_f32(float f) {
    uint32_t u = __float_as_uint(f);
    return (u & 0x80000000u) ? ~u : (u | 0x80000000u);
}

// ---------------------------------------------------------------------------
// Kernel A: rank-by-counting sort (stable, exact). Key = (~ord(score)<<32)|i,
// all keys distinct -> rank = #{j: key_j < key_i} is the exact permutation of
// jnp.argsort(-scores). Register-blocked: thread owns R=4 row keys in VGPRs,
// so each wave-uniform b128 broadcast (2 col keys) feeds 16 VALU instrs --
// the LDS pipe (which bound the previous versions at ~1 broadcast per 4 VALU
// cycles) drops to 1 per 32 VALU cycles. 16 column-segments x 128 cols per
// block, partial ranks combined via LDS psum. Grid 256 blocks = 1/CU,
// 4 waves/SIMD, VALU-bound at ~3.3 us chip floor.
// ---------------------------------------------------------------------------
__global__ __launch_bounds__(1024) void nms_rank(const float* __restrict__ pred,
                                                 float4* __restrict__ sortedBox) {
    __shared__ uint64_t keys[NN];          // 16 KB
    __shared__ int      psum[16][256];     // 16 KB
    const int b   = blockIdx.y;
    const int blk = blockIdx.x;            // 8 blocks/batch, 256 rows each
    const int tid = threadIdx.x;
    const float* p = pred + (size_t)b * NN * 5;

    for (int i = tid; i < NN; i += 1024) {
        float sc = p[i * 5 + 0];
        keys[i] = ((uint64_t)(~ordered_f32(sc)) << 32) | (uint32_t)i;
    }
    __syncthreads();

    const int seg  = tid >> 6;             // 16 segments (1 wave each)
    const int lane = tid & 63;

    uint64_t myk[4];
    int      cnt[4] = {0, 0, 0, 0};
#pragma unroll
    for (int r = 0; r < 4; ++r)            // distributed reads (2-way, free)
        myk[r] = keys[blk * 256 + lane + 64 * r];

    const ulonglong2* k2 = (const ulonglong2*)keys + seg * 64; // cols [seg*128, +128)
#pragma unroll 8
    for (int jj = 0; jj < 64; ++jj) {      // wave-uniform broadcast (1 DS / 16 VALU)
        ulonglong2 kk = k2[jj];
#pragma unroll
        for (int r = 0; r < 4; ++r)
            cnt[r] += (kk.x < myk[r]) + (kk.y < myk[r]);
    }
#pragma unroll
    for (int r = 0; r < 4; ++r)
        psum[seg][lane + 64 * r] = cnt[r];
    __syncthreads();

    if (tid < 256) {
        int rank = 0;
#pragma unroll
        for (int s = 0; s < 16; ++s) rank += psum[s][tid];
        const float* q = p + (size_t)(blk * 256 + tid) * 5;
        sortedBox[(size_t)b * NN + rank] = make_float4(q[1], q[2], q[3], q[4]);
    }
}

// ---------------------------------------------------------------------------
// Kernel B: suppression bit matrix, rows < ROWCAP only, upper triangle only.
// Wave-tile = 64 rows x 32 cols; lane = row (box in 4 VGPRs). Col boxes and
// c_j = 0.5f*area_j staged in LDS per block (128 cols, 2.5 KB) and streamed
// as wave-uniform broadcasts. Bit k set in place (cndmask(1<<k)+or, 2 VALU).
// No ballot, no cross-lane, stores already row-major (1 u32 per lane).
// Exact ref semantics: RN(inter/aj) >= 0.5  <=>  inter >= 0.5f*aj (the true
// threshold c - c*2^-25 lies in (pred(c), c); no f32 exists there).
// Word ct of row i is written iff ct >= 2*(i>>6)  (== walk's validity mask
// (lane>>1) >= (i>>6)); diagonal-overlap bits masked at write.
// ---------------------------------------------------------------------------
__global__ __launch_bounds__(256) void nms_pairs(const float4* __restrict__ sortedBox,
                                                 uint32_t* __restrict__ M) {
    __shared__ float4 sCol[128];
    __shared__ float  sC[128];
    const int b  = blockIdx.z;
    const int rt = blockIdx.y;             // row tile: 4 x 64 rows (ROWCAP=256)
    const int cg = blockIdx.x;             // col group: 16 x 128 cols
    const int tid  = threadIdx.x;
    const int wave = tid >> 6;
    const int lane = tid & 63;

    if (cg * 4 + 3 < 2 * rt) return;       // whole block below diagonal band

    const float4* box = sortedBox + (size_t)b * NN;

    if (tid < 128) {                       // stage 128 col boxes + thresholds
        float4 v = box[cg * 128 + tid];
        sCol[tid] = v;
        sC[tid]   = 0.5f * ((v.z - v.x) * (v.w - v.y));
    }
    __syncthreads();

    const int ct = cg * 4 + wave;          // col tile: 32 cols
    if (ct < 2 * rt) return;               // wave below diagonal band

    const int i = rt * 64 + lane;          // this lane's row
    const float4 bi = box[i];              // per-lane row box

    uint32_t rowword = 0;
    const int kbase = (wave & 3) * 32;
#pragma unroll
    for (int k = 0; k < 32; ++k) {
        float4 cb = sCol[kbase + k];       // wave-uniform broadcast
        float  c  = sC[kbase + k];
        float il = fmaxf(bi.x, cb.x);
        float iy = fmaxf(bi.y, cb.y);
        float ir = fminf(bi.z, cb.z);
        float ib = fminf(bi.w, cb.w);
        float inter = fmaxf(ir - il, 0.0f) * fmaxf(ib - iy, 0.0f);
        rowword |= (inter >= c) ? (1u << k) : 0u;   // bit k = col 32ct+k
    }

    const int d = i - ct * 32;             // mask cols j <= i (diagonal tiles)
    uint32_t um = (d < 0) ? 0xFFFFFFFFu : ((d >= 31) ? 0u : (0xFFFFFFFFu << (d + 1)));
    rowword &= um;

    M[((size_t)b * NN + i) * NW + ct] = rowword;
}

// ---------------------------------------------------------------------------
// Kernel C: serial greedy walk, one wave per batch. Lane L owns keep bits for
// j in [32L, 32L+32). Word L of row i valid only if (L>>1) >= (i>>6). Early
// exit at 100 kept. If 100 not reached by ROWCAP (pathological inputs only),
// computes remaining rows' suppression on the fly with identical semantics.
// ---------------------------------------------------------------------------
__global__ __launch_bounds__(64) void nms_walk(const uint32_t* __restrict__ M,
                                               const float4* __restrict__ sortedBox,
                                               float* __restrict__ out) {
    __shared__ int slots[NR];
    const int b    = blockIdx.x;
    const int lane = threadIdx.x;
    const uint32_t* Mb = M + (size_t)b * NN * NW;
    const float4* box  = sortedBox + (size_t)b * NN;

    uint32_t keep = 0xFFFFFFFFu;
    int count = 0;

    for (int i0 = 0; i0 < ROWCAP; i0 += 8) {
        uint32_t rr[8];
#pragma unroll
        for (int k = 0; k < 8; ++k)                // 8 independent loads in flight
            rr[k] = Mb[(size_t)(i0 + k) * NW + lane];
#pragma unroll
        for (int k = 0; k < 8; ++k) {
            const int i = i0 + k;
            uint32_t kw = __shfl(keep, i >> 5);
            if ((kw >> (i & 31)) & 1u) {           // box i survives -> suppress row
                uint32_t vm = ((lane >> 1) >= (i >> 6)) ? rr[k] : 0u;
                keep &= ~vm;
                if (lane == 0 && count < NR) slots[count] = i;
                ++count;
            }
        }
        if (count >= NR) break;                    // first 100 kept are final
    }

    // Fallback (correctness only; not expected to execute for this input).
    if (count < NR) {
        for (int i = ROWCAP; i < NN && count < NR; ++i) {
            uint32_t kw = __shfl(keep, i >> 5);
            if ((kw >> (i & 31)) & 1u) {
                float4 bi = box[i];                // wave-uniform broadcast
                uint32_t kill = 0;
                for (int t = 0; t < 32; ++t) {
                    int j = lane * 32 + t;
                    if (j > i) {
                        float4 bj = box[j];
                        float c  = 0.5f * ((bj.z - bj.x) * (bj.w - bj.y));
                        float il = fmaxf(bi.x, bj.x);
                        float iy = fmaxf(bi.y, bj.y);
                        float ir = fminf(bi.z, bj.z);
                        float ib = fminf(bi.w, bj.w);
                        float inter = fmaxf(ir - il, 0.0f) * fmaxf(ib - iy, 0.0f);
                        if (inter >= c) kill |= (1u << t);
                    }
                }
                keep &= ~kill;
                if (lane == 0 && count < NR) slots[count] = i;
                ++count;
            }
        }
    }
    __syncthreads();

    for (int s = lane; s < NR; s += 64) {
        float x = 0.f, y = 0.f, z = 0.f;
        if (s < count) {
            float4 q = box[slots[s]];
            x = q.y; y = q.z; z = q.w;             // vals = (top, right, bottom)
        }
        float* o = out + ((size_t)b * NR + s) * 3;
        o[0] = x; o[1] = y; o[2] = z;
    }
}

// ---------------------------------------------------------------------------
extern "C" void kernel_launch(void* const* d_in, const int* in_sizes, int n_in,
                              void* d_out, int out_size, void* d_ws, size_t ws_size,
                              hipStream_t stream) {
    const float* pred = (const float*)d_in[0];
    float* out = (float*)d_out;
    char* ws = (char*)d_ws;

    float4*   sortedBox = (float4*)ws;                                        // 1 MB
    uint32_t* M         = (uint32_t*)(ws + (size_t)NB * NN * sizeof(float4)); // 2 MB used

    nms_rank <<<dim3(8, NB), 1024, 0, stream>>>(pred, sortedBox);
    nms_pairs<<<dim3(16, 4, NB), 256, 0, stream>>>(sortedBox, M);
    nms_walk <<<NB, 64, 0, stream>>>(M, sortedBox, out);
}